// Round 16
// baseline (805.654 us; speedup 1.0000x reference)
//
#include <hip/hip_runtime.h>
#include <math.h>

#define E 256
#define H 8
#define HD 32
#define FF 1024
#define LE 4
#define LDN 3
#define KQ 8
#define CDIM 4
#define DIN 4
#define BATCH 16
#define SEQ 512

typedef __attribute__((ext_vector_type(8))) short s8b;
typedef __attribute__((ext_vector_type(4))) float f32x4;

__device__ __forceinline__ float gelu_f(float x) {
  return 0.5f * x * (1.f + erff(x * 0.70710678118654752f));
}

__device__ __forceinline__ unsigned short f2b(float f) {
  union { float f; unsigned u; } a;
  a.f = f;
  unsigned r = (a.u + 0x7fffu + ((a.u >> 16) & 1u)) >> 16;
  return (unsigned short)r;
}

__device__ __forceinline__ float b2f(unsigned short u) {
  union { unsigned u; float f; } a;
  a.u = ((unsigned)u) << 16;
  return a.f;
}

__device__ __forceinline__ void gload16(const unsigned short* g, unsigned short* l) {
  __builtin_amdgcn_global_load_lds((const __attribute__((address_space(1))) void*)g,
                                   (__attribute__((address_space(3))) void*)l, 16, 0, 0);
}

// ---------------- bf16 MFMA GEMM 64x128 tile, bf16/QKV-split output ----------------
// OMODE: 1 = bf16 row-major, 2 = QKV split (headmajor Q,K + transposed V)
template <int GELU, int OMODE>
__global__ __launch_bounds__(256) void mfma_gemm64o_kernel(
    const unsigned short* __restrict__ A, const unsigned short* __restrict__ Wt,
    const float* __restrict__ bias, unsigned short* __restrict__ outb,
    unsigned short* __restrict__ vtb, int N, int K) {
  __shared__ __align__(16) unsigned short As[64 * 32];
  __shared__ __align__(16) unsigned short Bs[128 * 32];
  int tid = threadIdx.x;
  int lane = tid & 63, w = tid >> 6;
  int row0 = blockIdx.y * 64, col0 = blockIdx.x * 128;
  int wr = (w >> 1) * 32, wc = (w & 1) * 64;
  f32x4 acc[2][4] = {};

  int sc = lane & 3;
  int srA = w * 16 + (lane >> 2);
  int gcA = (sc ^ ((srA >> 1) & 3)) * 8;
  const unsigned short* ApA = A + (size_t)(row0 + srA) * K + gcA;
  unsigned short* lA = As + (w * 16) * 32;
  int sr0 = w * 32 + (lane >> 2);
  int sr1 = sr0 + 16;
  int gc0 = (sc ^ ((sr0 >> 1) & 3)) * 8;
  int gc1 = (sc ^ ((sr1 >> 1) & 3)) * 8;
  const unsigned short* Bp0 = Wt + (size_t)(col0 + sr0) * K + gc0;
  const unsigned short* Bp1 = Wt + (size_t)(col0 + sr1) * K + gc1;
  unsigned short* lB0 = Bs + (w * 32) * 32;
  unsigned short* lB1 = Bs + (w * 32 + 16) * 32;

  for (int k0 = 0; k0 < K; k0 += 32) {
    __syncthreads();
    gload16(ApA + k0, lA);
    gload16(Bp0 + k0, lB0);
    gload16(Bp1 + k0, lB1);
    __syncthreads();
    int krow = lane & 15, kq = lane >> 4;
    s8b afr[2], bfr[4];
    #pragma unroll
    for (int mi = 0; mi < 2; ++mi) {
      int r = wr + mi * 16 + krow;
      afr[mi] = *(const s8b*)(As + r * 32 + ((kq ^ ((r >> 1) & 3)) * 8));
    }
    #pragma unroll
    for (int ni = 0; ni < 4; ++ni) {
      int r = wc + ni * 16 + krow;
      bfr[ni] = *(const s8b*)(Bs + r * 32 + ((kq ^ ((r >> 1) & 3)) * 8));
    }
    #pragma unroll
    for (int mi = 0; mi < 2; ++mi)
      #pragma unroll
      for (int ni = 0; ni < 4; ++ni)
        acc[mi][ni] = __builtin_amdgcn_mfma_f32_16x16x32_bf16(afr[mi], bfr[ni], acc[mi][ni], 0, 0, 0);
  }

  int cl = lane & 15, rb = (lane >> 4) * 4;
  #pragma unroll
  for (int ni = 0; ni < 4; ++ni) {
    int col = col0 + wc + ni * 16 + cl;
    float bv = bias[col];
    #pragma unroll
    for (int mi = 0; mi < 2; ++mi) {
      #pragma unroll
      for (int j = 0; j < 4; ++j) {
        int row = row0 + wr + mi * 16 + rb + j;
        float v = acc[mi][ni][j] + bv;
        if (GELU) v = gelu_f(v);
        if (OMODE == 1) {
          outb[(size_t)row * N + col] = f2b(v);
        } else {
          int b = row >> 9, s = row & 511;
          int sect = col >> 8, hh = (col >> 5) & 7, d = col & 31;
          if (sect < 2)
            outb[((((size_t)sect * BATCH + b) * H + hh) * SEQ + s) * HD + d] = f2b(v);
          else
            vtb[(((size_t)b * H + hh) * HD + d) * SEQ + s] = f2b(v);
        }
      }
    }
  }
}

// ---------------- bf16 MFMA GEMM 32x128 tile, fp32 out + bias + resid (+opt bf16 mirror) ----
template <int BF16OUT>
__global__ __launch_bounds__(256) void mfma_gemm32_kernel(
    const unsigned short* __restrict__ A, const unsigned short* __restrict__ Wt,
    const float* __restrict__ bias, const float* __restrict__ resid,
    float* __restrict__ outf, unsigned short* __restrict__ outb, int M, int N, int K) {
  __shared__ __align__(16) unsigned short As[32 * 32];
  __shared__ __align__(16) unsigned short Bs[128 * 32];
  int tid = threadIdx.x;
  int lane = tid & 63, w = tid >> 6;
  int row0 = blockIdx.y * 32, col0 = blockIdx.x * 128;
  int wr = (w & 1) * 16, wc = (w >> 1) * 64;
  f32x4 acc[4] = {};

  int sc = lane & 3;
  int srA = w * 16 + (lane >> 2);
  int gcA = (sc ^ ((srA >> 1) & 3)) * 8;
  const unsigned short* ApA = A + (size_t)(row0 + (srA & 31)) * K + gcA;
  unsigned short* lA = As + ((w & 1) * 16) * 32;
  int sr0 = w * 32 + (lane >> 2);
  int sr1 = sr0 + 16;
  int gc0 = (sc ^ ((sr0 >> 1) & 3)) * 8;
  int gc1 = (sc ^ ((sr1 >> 1) & 3)) * 8;
  const unsigned short* Bp0 = Wt + (size_t)(col0 + sr0) * K + gc0;
  const unsigned short* Bp1 = Wt + (size_t)(col0 + sr1) * K + gc1;
  unsigned short* lB0 = Bs + (w * 32) * 32;
  unsigned short* lB1 = Bs + (w * 32 + 16) * 32;

  for (int k0 = 0; k0 < K; k0 += 32) {
    __syncthreads();
    if (w < 2) gload16(ApA + k0, lA);
    gload16(Bp0 + k0, lB0);
    gload16(Bp1 + k0, lB1);
    __syncthreads();
    int krow = lane & 15, kq = lane >> 4;
    int ra = wr + krow;
    s8b afr = *(const s8b*)(As + ra * 32 + ((kq ^ ((ra >> 1) & 3)) * 8));
    #pragma unroll
    for (int ni = 0; ni < 4; ++ni) {
      int r = wc + ni * 16 + krow;
      s8b bfr = *(const s8b*)(Bs + r * 32 + ((kq ^ ((r >> 1) & 3)) * 8));
      acc[ni] = __builtin_amdgcn_mfma_f32_16x16x32_bf16(afr, bfr, acc[ni], 0, 0, 0);
    }
  }

  int cl = lane & 15, rb = (lane >> 4) * 4;
  #pragma unroll
  for (int ni = 0; ni < 4; ++ni) {
    int col = col0 + wc + ni * 16 + cl;
    float bv = bias[col];
    #pragma unroll
    for (int j = 0; j < 4; ++j) {
      int row = row0 + wr + rb + j;
      float v = acc[ni][j] + bv + resid[(size_t)row * N + col];
      outf[(size_t)row * N + col] = v;
      if (BF16OUT) outb[(size_t)row * N + col] = f2b(v);
    }
  }
}

// ---------------- MFMA encoder attention (T5: setprio around MFMA clusters) ----------------
__global__ __launch_bounds__(256) void mfma_attn_kernel(
    const unsigned short* __restrict__ qkb, const unsigned short* __restrict__ vt,
    const float2* __restrict__ carr, const float* __restrict__ gamma_p,
    unsigned short* __restrict__ out) {
  __shared__ __align__(16) unsigned short P[4][16 * 64];
  int tid = threadIdx.x, lane = tid & 63, w = tid >> 6;
  int qt = blockIdx.x, h = blockIdx.y, b = blockIdx.z;
  int q0 = qt * 64 + w * 16;
  const unsigned short* qh = qkb + (((size_t)b * H + h) * SEQ) * HD;
  const unsigned short* kh = qkb + ((((size_t)BATCH + b) * H + h) * SEQ) * HD;
  const unsigned short* vh = vt + (((size_t)b * H + h) * HD) * SEQ;
  int r16 = lane & 15, q4 = lane >> 4;
  s8b qa = *(const s8b*)(qh + (size_t)(q0 + r16) * HD + q4 * 8);
  float eq[4], pq[4];
  #pragma unroll
  for (int j = 0; j < 4; ++j) {
    float2 c = carr[b * SEQ + q0 + q4 * 4 + j];
    eq[j] = c.x; pq[j] = c.y;
  }
  float gam = gamma_p[0] * 0.49999999500000004f;
  const float scale = 0.17677669529663687f;
  float m[4], lsum[4];
  #pragma unroll
  for (int j = 0; j < 4; ++j) { m[j] = -1e30f; lsum[j] = 0.f; }
  f32x4 o0 = {}, o1 = {};
  const f32x4 zf = {0.f, 0.f, 0.f, 0.f};
  unsigned short* pw = &P[w][0];

  for (int t = 0; t < SEQ / 64; ++t) {
    int k0 = t * 64;
    f32x4 sf[4];
    __builtin_amdgcn_s_setprio(1);
    #pragma unroll
    for (int f = 0; f < 4; ++f) {
      s8b bk = *(const s8b*)(kh + (size_t)(k0 + f * 16 + r16) * HD + q4 * 8);
      sf[f] = __builtin_amdgcn_mfma_f32_16x16x32_bf16(qa, bk, zf, 0, 0, 0);
    }
    __builtin_amdgcn_s_setprio(0);
    float ek[4], pk[4];
    #pragma unroll
    for (int f = 0; f < 4; ++f) {
      float2 c = carr[b * SEQ + k0 + f * 16 + r16];
      ek[f] = c.x; pk[f] = c.y;
    }
    float sc_[4][4];
    float tmax[4] = {-1e30f, -1e30f, -1e30f, -1e30f};
    #pragma unroll
    for (int f = 0; f < 4; ++f)
      #pragma unroll
      for (int j = 0; j < 4; ++j) {
        float de = eq[j] - ek[f], dp = pq[j] - pk[f];
        float v = sf[f][j] * scale - gam * (de * de + dp * dp);
        sc_[f][j] = v;
        tmax[j] = fmaxf(tmax[j], v);
      }
    #pragma unroll
    for (int j = 0; j < 4; ++j) {
      #pragma unroll
      for (int off = 1; off < 16; off <<= 1)
        tmax[j] = fmaxf(tmax[j], __shfl_xor(tmax[j], off));
      float mn = fmaxf(m[j], tmax[j]);
      float al = __expf(m[j] - mn);
      m[j] = mn;
      lsum[j] *= al;
      o0[j] *= al;
      o1[j] *= al;
    }
    __syncthreads();
    #pragma unroll
    for (int f = 0; f < 4; ++f)
      #pragma unroll
      for (int j = 0; j < 4; ++j) {
        float p = __expf(sc_[f][j] - m[j]);
        lsum[j] += p;
        int prow = q4 * 4 + j;
        int c = f * 16 + r16;
        int chunk = (c >> 3) ^ (prow & 7);
        pw[prow * 64 + chunk * 8 + (c & 7)] = f2b(p);
      }
    __syncthreads();
    __builtin_amdgcn_s_setprio(1);
    #pragma unroll
    for (int ks = 0; ks < 2; ++ks) {
      int chunk = (ks * 4 + q4) ^ (r16 & 7);
      s8b pa = *(const s8b*)(pw + r16 * 64 + chunk * 8);
      s8b v0 = *(const s8b*)(vh + (size_t)r16 * SEQ + k0 + ks * 32 + q4 * 8);
      s8b v1 = *(const s8b*)(vh + (size_t)(16 + r16) * SEQ + k0 + ks * 32 + q4 * 8);
      o0 = __builtin_amdgcn_mfma_f32_16x16x32_bf16(pa, v0, o0, 0, 0, 0);
      o1 = __builtin_amdgcn_mfma_f32_16x16x32_bf16(pa, v1, o1, 0, 0, 0);
    }
    __builtin_amdgcn_s_setprio(0);
  }
  #pragma unroll
  for (int j = 0; j < 4; ++j) {
    #pragma unroll
    for (int off = 1; off < 16; off <<= 1)
      lsum[j] += __shfl_xor(lsum[j], off);
    float inv = 1.f / lsum[j];
    size_t rbase = ((size_t)(b * SEQ + q0 + q4 * 4 + j)) * E + h * HD;
    out[rbase + r16] = f2b(o0[j] * inv);
    out[rbase + 16 + r16] = f2b(o1[j] * inv);
  }
}

__global__ void coords_kernel(const float* __restrict__ x, float2* __restrict__ carr) {
  int i = blockIdx.x * 256 + threadIdx.x;
  if (i >= BATCH * SEQ) return;
  carr[i] = make_float2(x[(size_t)i * DIN + 1], x[(size_t)i * DIN + 2]);
}

// merged conversion of the 4 encoder weight tensors
__global__ void cvt_all_kernel(const float* __restrict__ w0, const float* __restrict__ w1,
                               const float* __restrict__ w2, const float* __restrict__ w3,
                               unsigned short* __restrict__ o0, unsigned short* __restrict__ o1,
                               unsigned short* __restrict__ o2, unsigned short* __restrict__ o3) {
  const int n0 = LE * 3 * E * E / 4, n1 = LE * E * E / 4;
  const int n2 = LE * FF * E / 4, n3 = LE * E * FF / 4;
  int j = blockIdx.x * 256 + threadIdx.x;
  const float* src; unsigned short* dst;
  if (j < n0) { src = w0; dst = o0; }
  else if ((j -= n0) < n1) { src = w1; dst = o1; }
  else if ((j -= n1) < n2) { src = w2; dst = o2; }
  else if ((j -= n2) < n3) { src = w3; dst = o3; }
  else return;
  float4 v = ((const float4*)src)[j];
  ushort4 o;
  o.x = f2b(v.x); o.y = f2b(v.y); o.z = f2b(v.z); o.w = f2b(v.w);
  ((ushort4*)dst)[j] = o;
}

// remap decoder KV weights [LDN][3E][E] -> combined [3*512][256] bf16 + bias [1536]
__global__ void kvw_remap_kernel(const float* __restrict__ w, const float* __restrict__ b,
                                 unsigned short* __restrict__ wout, float* __restrict__ bout) {
  int i = blockIdx.x * 256 + threadIdx.x;
  if (i < 1536) bout[i] = b[(i >> 9) * 768 + 256 + (i & 511)];
  if (i >= 98304) return;
  int row = i >> 6, cc = i & 63;
  int l = row >> 9, rr = row & 511;
  const float* src = w + ((size_t)l * 768 + 256 + rr) * 256 + cc * 4;
  float4 v = *(const float4*)src;
  ushort4 o;
  o.x = f2b(v.x); o.y = f2b(v.y); o.z = f2b(v.z); o.w = f2b(v.w);
  *(ushort4*)(wout + (size_t)row * 256 + cc * 4) = o;
}

// input_proj + BN(eval) + GELU + layer0 ln1, writing h (fp32) and hn (bf16 LN'd)
__global__ __launch_bounds__(256) void input_proj_ln_kernel(
    const float* __restrict__ x, const float* __restrict__ in_w, const float* __restrict__ in_b,
    const float* __restrict__ bn_w, const float* __restrict__ bn_b,
    const float* __restrict__ nw, const float* __restrict__ nb,
    float* __restrict__ h, unsigned short* __restrict__ hn) {
  __shared__ float sred[4];
  __shared__ float vred[4];
  int row = blockIdx.x, e = threadIdx.x;
  const float* xr = x + (size_t)row * DIN;
  float v = in_b[e];
  #pragma unroll
  for (int i = 0; i < DIN; ++i) v += xr[i] * in_w[e * DIN + i];
  v = v * (1.0f / sqrtf(1.0f + 1e-5f)) * bn_w[e] + bn_b[e];
  v = gelu_f(v);
  h[(size_t)row * 256 + e] = v;
  int lane = e & 63, w = e >> 6;
  float s = v;
  #pragma unroll
  for (int off = 32; off > 0; off >>= 1) s += __shfl_xor(s, off);
  if (lane == 0) sred[w] = s;
  __syncthreads();
  float mean = (sred[0] + sred[1] + sred[2] + sred[3]) * (1.f / 256);
  float d = v - mean;
  float vr = d * d;
  #pragma unroll
  for (int off = 32; off > 0; off >>= 1) vr += __shfl_xor(vr, off);
  if (lane == 0) vred[w] = vr;
  __syncthreads();
  float inv = rsqrtf((vred[0] + vred[1] + vred[2] + vred[3]) * (1.f / 256) + 1e-5f);
  hn[(size_t)row * 256 + e] = f2b(d * inv * nw[e] + nb[e]);
}

// 4 rows per block (256 threads, wave per row)
__global__ __launch_bounds__(256) void ln_bf16_kernel(
    const float* __restrict__ in, const float* __restrict__ w,
    const float* __restrict__ b, unsigned short* __restrict__ out) {
  int r = blockIdx.x * 4 + (threadIdx.x >> 6);
  int l = threadIdx.x & 63;
  const float* p = in + (size_t)r * E;
  float v0 = p[l], v1 = p[l + 64], v2 = p[l + 128], v3 = p[l + 192];
  float s = v0 + v1 + v2 + v3;
  for (int off = 32; off > 0; off >>= 1) s += __shfl_xor(s, off);
  float mean = s * (1.f / E);
  float d0 = v0 - mean, d1 = v1 - mean, d2 = v2 - mean, d3 = v3 - mean;
  float var = d0 * d0 + d1 * d1 + d2 * d2 + d3 * d3;
  for (int off = 32; off > 0; off >>= 1) var += __shfl_xor(var, off);
  float inv = rsqrtf(var * (1.f / E) + 1e-5f);
  unsigned short* o = out + (size_t)r * E;
  o[l]       = f2b(d0 * inv * w[l]       + b[l]);
  o[l + 64]  = f2b(d1 * inv * w[l + 64]  + b[l + 64]);
  o[l + 128] = f2b(d2 * inv * w[l + 128] + b[l + 128]);
  o[l + 192] = f2b(d3 * inv * w[l + 192] + b[l + 192]);
}

// ========== decoder stage kernels ==========

template <int N, int GELU>
__global__ __launch_bounds__(256) void dec_ln_gemv_kernel(
    const float* __restrict__ t, const float* __restrict__ nw, const float* __restrict__ nb,
    const float* __restrict__ W, const float* __restrict__ bias, float* __restrict__ outg) {
  __shared__ float X[8][256];
  __shared__ float Pp[4][64][9];
  int b = blockIdx.x, by = blockIdx.y, tid = threadIdx.x;
  const float* tg = t + (size_t)b * 2048;
  int w = tid >> 6, l = tid & 63;
  #pragma unroll
  for (int rr = 0; rr < 2; ++rr) {
    int r = w * 2 + rr;
    float v0 = tg[r * 256 + l], v1 = tg[r * 256 + 64 + l];
    float v2 = tg[r * 256 + 128 + l], v3 = tg[r * 256 + 192 + l];
    float s = v0 + v1 + v2 + v3;
    for (int o = 32; o > 0; o >>= 1) s += __shfl_xor(s, o);
    float mean = s * (1.f / 256);
    float d0 = v0 - mean, d1 = v1 - mean, d2 = v2 - mean, d3 = v3 - mean;
    float var = d0 * d0 + d1 * d1 + d2 * d2 + d3 * d3;
    for (int o = 32; o > 0; o >>= 1) var += __shfl_xor(var, o);
    float inv = rsqrtf(var * (1.f / 256) + 1e-5f);
    X[r][l] = d0 * inv * nw[l] + nb[l];
    X[r][l + 64] = d1 * inv * nw[l + 64] + nb[l + 64];
    X[r][l + 128] = d2 * inv * nw[l + 128] + nb[l + 128];
    X[r][l + 192] = d3 * inv * nw[l + 192] + nb[l + 192];
  }
  __syncthreads();
  int j = tid & 63, kq = tid >> 6;
  int col = by * 64 + j;
  const float4* wp = (const float4*)(W + (size_t)col * 256 + kq * 64);
  float acc[8] = {};
  #pragma unroll
  for (int kk = 0; kk < 16; ++kk) {
    float4 wv = wp[kk];
    int base = kq * 64 + kk * 4;
    #pragma unroll
    for (int r = 0; r < 8; ++r) {
      float4 xv = *(const float4*)&X[r][base];
      acc[r] += xv.x * wv.x + xv.y * wv.y + xv.z * wv.z + xv.w * wv.w;
    }
  }
  #pragma unroll
  for (int r = 0; r < 8; ++r) Pp[kq][j][r] = acc[r];
  __syncthreads();
  for (int i = tid; i < 512; i += 256) {
    int r = i & 7, j2 = i >> 3;
    float v = Pp[0][j2][r] + Pp[1][j2][r] + Pp[2][j2][r] + Pp[3][j2][r] + bias[by * 64 + j2];
    if (GELU) v = gelu_f(v);
    outg[((size_t)b * 8 + r) * N + by * 64 + j2] = v;
  }
}

// fused: self-attention (recomputed per col-block) + sout GEMV chunk + resid into t
__global__ __launch_bounds__(256) void dec_selfattn_sout_kernel(
    const float* __restrict__ qkvg, const float* __restrict__ W, const float* __restrict__ bias,
    float* __restrict__ t) {
  __shared__ float QK[8][768];
  __shared__ float S[512];
  __shared__ float X[8][256];
  __shared__ float Pp[4][64][9];
  int b = blockIdx.x, by = blockIdx.y, tid = threadIdx.x;
  const float* qg = qkvg + (size_t)b * 8 * 768;
  for (int i = tid; i < 6144; i += 256) ((float*)QK)[i] = qg[i];
  __syncthreads();
  for (int t2 = tid; t2 < 512; t2 += 256) {
    int h = t2 >> 6, q = (t2 >> 3) & 7, k = t2 & 7;
    const float* qp = &QK[q][h * 32];
    const float* kp = &QK[k][256 + h * 32];
    float d = 0.f;
    #pragma unroll
    for (int jj = 0; jj < 32; ++jj) d += qp[jj] * kp[jj];
    S[t2] = d * 0.17677669529663687f;
  }
  __syncthreads();
  if (tid < 64) {
    float* row = &S[tid * 8];
    float m = row[0];
    #pragma unroll
    for (int k = 1; k < 8; ++k) m = fmaxf(m, row[k]);
    float sum = 0.f;
    #pragma unroll
    for (int k = 0; k < 8; ++k) { float e = __expf(row[k] - m); row[k] = e; sum += e; }
    float inv = 1.f / sum;
    #pragma unroll
    for (int k = 0; k < 8; ++k) row[k] *= inv;
  }
  __syncthreads();
  for (int i = tid; i < 2048; i += 256) {
    int q = i >> 8, c = i & 255, h = c >> 5;
    const float* pr = &S[h * 64 + q * 8];
    float acc = 0.f;
    #pragma unroll
    for (int k = 0; k < 8; ++k) acc += pr[k] * QK[k][512 + c];
    X[q][c] = acc;
  }
  __syncthreads();
  int j = tid & 63, kq = tid >> 6;
  int col = by * 64 + j;
  const float4* wp = (const float4*)(W + (size_t)col * 256 + kq * 64);
  float acc[8] = {};
  #pragma unroll
  for (int kk = 0; kk < 16; ++kk) {
    float4 wv = wp[kk];
    int base = kq * 64 + kk * 4;
    #pragma unroll
    for (int r = 0; r < 8; ++r) {
      float4 xv = *(const float4*)&X[r][base];
      acc[r] += xv.x * wv.x + xv.y * wv.y + xv.z * wv.z + xv.w * wv.w;
    }
  }
  #pragma unroll
  for (int r = 0; r < 8; ++r) Pp[kq][j][r] = acc[r];
  __syncthreads();
  for (int i = tid; i < 512; i += 256) {
    int r = i & 7, j2 = i >> 3;
    float v = Pp[0][j2][r] + Pp[1][j2][r] + Pp[2][j2][r] + Pp[3][j2][r] + bias[by * 64 + j2];
    t[((size_t)b * 8 + r) * 256 + by * 64 + j2] += v;
  }
}

__global__ __launch_bounds__(256) void dec_gemv_resid_kernel(
    const float* __restrict__ Xg, const float* __restrict__ W, const float* __restrict__ bias,
    float* __restrict__ t) {
  __shared__ float X[8][256];
  __shared__ float Pp[4][64][9];
  int b = blockIdx.x, by = blockIdx.y, tid = threadIdx.x;
  const float* xg = Xg + (size_t)b * 2048;
  for (int i = tid; i < 2048; i += 256) ((float*)X)[i] = xg[i];
  __syncthreads();
  int j = tid & 63, kq = tid >> 6;
  int col = by * 64 + j;
  const float4* wp = (const float4*)(W + (size_t)col * 256 + kq * 64);
  float acc[8] = {};
  #pragma unroll
  for (int kk = 0; kk < 16; ++kk) {
    float4 wv = wp[kk];
    int base = kq * 64 + kk * 4;
    #pragma unroll
    for (int r = 0; r < 8; ++r) {
      float4 xv = *(const float4*)&X[r][base];
      acc[r] += xv.x * wv.x + xv.y * wv.y + xv.z * wv.z + xv.w * wv.w;
    }
  }
  #pragma unroll
  for (int r = 0; r < 8; ++r) Pp[kq][j][r] = acc[r];
  __syncthreads();
  for (int i = tid; i < 512; i += 256) {
    int r = i & 7, j2 = i >> 3;
    float v = Pp[0][j2][r] + Pp[1][j2][r] + Pp[2][j2][r] + Pp[3][j2][r] + bias[by * 64 + j2];
    t[((size_t)b * 8 + r) * 256 + by * 64 + j2] += v;
  }
}

__global__ __launch_bounds__(256) void dec_ffn2_kernel(
    const float* __restrict__ MIDg, const float* __restrict__ W, const float* __restrict__ bias,
    float* __restrict__ t) {
  __shared__ float X[8][1024];
  __shared__ float Pp[4][64][9];
  int b = blockIdx.x, by = blockIdx.y, tid = threadIdx.x;
  const float* xg = MIDg + (size_t)b * 8192;
  for (int i = tid; i < 8192; i += 256) ((float*)X)[i] = xg[i];
  __syncthreads();
  int j = tid & 63, kq = tid >> 6;
  int col = by * 64 + j;
  const float4* wp = (const float4*)(W + (size_t)col * 1024 + kq * 256);
  float acc[8] = {};
  #pragma unroll 8
  for (int kk = 0; kk < 64; ++kk) {
    float4 wv = wp[kk];
    int base = kq * 256 + kk * 4;
    #pragma unroll
    for (int r = 0; r < 8; ++r) {
      float4 xv = *(const float4*)&X[r][base];
      acc[r] += xv.x * wv.x + xv.y * wv.y + xv.z * wv.z + xv.w * wv.w;
    }
  }
  #pragma unroll
  for (int r = 0; r < 8; ++r) Pp[kq][j][r] = acc[r];
  __syncthreads();
  for (int i = tid; i < 512; i += 256) {
    int r = i & 7, j2 = i >> 3;
    float v = Pp[0][j2][r] + Pp[1][j2][r] + Pp[2][j2][r] + Pp[3][j2][r] + bias[by * 64 + j2];
    t[((size_t)b * 8 + r) * 256 + by * 64 + j2] += v;
  }
}

// cross attention with fused ln2 + Q-projection: one block per (b,h,q) over bf16 KV
__global__ __launch_bounds__(256) void cross_attn_ln_kernel(
    const float* __restrict__ t, const float* __restrict__ nw, const float* __restrict__ nb,
    const float* __restrict__ cqw, const float* __restrict__ cqb,
    const unsigned short* __restrict__ KV, int koff, int voff, float* __restrict__ out) {
  __shared__ float X[256];
  __shared__ float sv[512];
  __shared__ float red[256];
  __shared__ float qv[32];
  __shared__ float pvred[8][32];
  __shared__ float sred[4], vred[4];
  int tid = threadIdx.x;
  int bid = blockIdx.x;
  int q = bid % KQ;
  int h = (bid / KQ) % H;
  int b = bid / (KQ * H);
  {
    float v = t[((size_t)(b * KQ + q)) * 256 + tid];
    int lane = tid & 63, w = tid >> 6;
    float s = v;
    #pragma unroll
    for (int off = 32; off > 0; off >>= 1) s += __shfl_xor(s, off);
    if (lane == 0) sred[w] = s;
    __syncthreads();
    float mean = (sred[0] + sred[1] + sred[2] + sred[3]) * (1.f / 256);
    float d = v - mean;
    float vr = d * d;
    #pragma unroll
    for (int off = 32; off > 0; off >>= 1) vr += __shfl_xor(vr, off);
    if (lane == 0) vred[w] = vr;
    __syncthreads();
    float inv = rsqrtf((vred[0] + vred[1] + vred[2] + vred[3]) * (1.f / 256) + 1e-5f);
    X[tid] = d * inv * nw[tid] + nb[tid];
  }
  __syncthreads();
  {
    int dd = tid >> 3, part = tid & 7;
    int col = h * HD + dd;
    const float4* wp = (const float4*)(cqw + (size_t)col * 256 + part * 32);
    float acc = 0.f;
    #pragma unroll
    for (int kk = 0; kk < 8; ++kk) {
      float4 wv = wp[kk];
      float4 xv = *(const float4*)&X[part * 32 + kk * 4];
      acc += xv.x * wv.x + xv.y * wv.y + xv.z * wv.z + xv.w * wv.w;
    }
    red[tid] = acc;
  }
  __syncthreads();
  if (tid < 32) {
    float acc = 0.f;
    #pragma unroll
    for (int p = 0; p < 8; ++p) acc += red[tid * 8 + p];
    qv[tid] = acc + cqb[h * HD + tid];
  }
  __syncthreads();
  const float scale = 0.17677669529663687f;
  for (int k = tid; k < SEQ; k += 256) {
    const unsigned short* kp = KV + ((size_t)(b * SEQ + k)) * 1536 + koff + h * HD;
    float d = 0.f;
    #pragma unroll
    for (int j4 = 0; j4 < 4; ++j4) {
      s8b kv8 = *(const s8b*)(kp + j4 * 8);
      #pragma unroll
      for (int j = 0; j < 8; ++j)
        d += qv[j4 * 8 + j] * b2f((unsigned short)kv8[j]);
    }
    sv[k] = d * scale;
  }
  __syncthreads();
  float m = -1e30f;
  for (int k = tid; k < SEQ; k += 256) m = fmaxf(m, sv[k]);
  red[tid] = m; __syncthreads();
  for (int s = 128; s > 0; s >>= 1) {
    if (tid < s) red[tid] = fmaxf(red[tid], red[tid + s]);
    __syncthreads();
  }
  m = red[0]; __syncthreads();
  float lsum = 0.f;
  for (int k = tid; k < SEQ; k += 256) { float e = __expf(sv[k] - m); sv[k] = e; lsum += e; }
  red[tid] = lsum; __syncthreads();
  for (int s = 128; s > 0; s >>= 1) {
    if (tid < s) red[tid] += red[tid + s];
    __syncthreads();
  }
  float denom = red[0];
  int d = tid & 31, g = tid >> 5;
  float acc = 0.f;
  for (int k = g; k < SEQ; k += 8)
    acc += sv[k] * b2f(KV[((size_t)(b * SEQ + k)) * 1536 + voff + h * HD + d]);
  pvred[g][d] = acc;
  __syncthreads();
  if (tid < 32) {
    float r = 0.f;
    #pragma unroll
    for (int gg = 0; gg < 8; ++gg) r += pvred[gg][tid];
    out[((size_t)(b * KQ + q)) * E + h * HD + tid] = r / denom;
  }
}

__global__ __launch_bounds__(256) void pool_gather_kernel(
    const float* __restrict__ mem, const int* __restrict__ pidx, float* __restrict__ pg) {
  __shared__ float red[8][32];
  int b = blockIdx.x, cy = blockIdx.y, tid = threadIdx.x;
  int c = cy * 32 + (tid & 31), g = tid >> 5;
  float s = 0.f;
  for (int r = g; r < SEQ; r += 8)
    s += mem[((size_t)b * SEQ + r) * E + c];
  red[g][tid & 31] = s;
  __syncthreads();
  if (tid < 32) {
    float t = 0.f;
    #pragma unroll
    for (int g2 = 0; g2 < 8; ++g2) t += red[g2][tid];
    pg[(size_t)b * 512 + 256 + cy * 32 + tid] = t * (1.f / SEQ);
    pg[(size_t)b * 512 + cy * 32 + tid] = mem[((size_t)b * SEQ + pidx[b]) * E + cy * 32 + tid];
  }
}

__global__ void cond_kernel(const float* __restrict__ pg, const float* __restrict__ c1w,
                            const float* __restrict__ c1b, const float* __restrict__ c2w,
                            const float* __restrict__ c2b, const float* __restrict__ qe,
                            float* __restrict__ t) {
  __shared__ float PG[512];
  __shared__ float C1[256];
  int b = blockIdx.x, c = threadIdx.x;
  PG[c] = pg[(size_t)b * 512 + c];
  PG[c + 256] = pg[(size_t)b * 512 + 256 + c];
  __syncthreads();
  const float4* wp = (const float4*)(c1w + (size_t)c * 512);
  float acc = c1b[c];
  #pragma unroll 8
  for (int kk = 0; kk < 128; ++kk) {
    float4 wv = wp[kk];
    int base = kk * 4;
    acc += PG[base] * wv.x + PG[base + 1] * wv.y + PG[base + 2] * wv.z + PG[base + 3] * wv.w;
  }
  C1[c] = gelu_f(acc);
  __syncthreads();
  const float4* wp2 = (const float4*)(c2w + (size_t)c * 256);
  float acc2 = c2b[c];
  #pragma unroll 8
  for (int kk = 0; kk < 64; ++kk) {
    float4 wv = wp2[kk];
    int base = kk * 4;
    acc2 += C1[base] * wv.x + C1[base + 1] * wv.y + C1[base + 2] * wv.z + C1[base + 3] * wv.w;
  }
  #pragma unroll
  for (int k = 0; k < KQ; ++k)
    t[((size_t)b * KQ + k) * E + c] = qe[k * E + c] + acc2;
}

__global__ void head_kernel(const float* __restrict__ t,
                            const float* __restrict__ childw, const float* __restrict__ childb,
                            const float* __restrict__ o1w, const float* __restrict__ o1b,
                            const float* __restrict__ o2w, const float* __restrict__ o2b,
                            float* __restrict__ out_child, float* __restrict__ out_obj) {
  __shared__ float tr[256];
  __shared__ float red[256];
  int r = blockIdx.x, c = threadIdx.x;
  tr[c] = t[(size_t)r * E + c];
  __syncthreads();
  const float4* wp = (const float4*)(o1w + (size_t)c * 256);
  float acc = o1b[c];
  #pragma unroll 8
  for (int kk = 0; kk < 64; ++kk) {
    float4 wv = wp[kk];
    int base = kk * 4;
    acc += tr[base] * wv.x + tr[base + 1] * wv.y + tr[base + 2] * wv.z + tr[base + 3] * wv.w;
  }
  red[c] = gelu_f(acc) * o2w[c];
  __syncthreads();
  for (int s = 128; s > 0; s >>= 1) {
    if (c < s) red[c] += red[c + s];
    __syncthreads();
  }
  if (c == 0) out_obj[r] = red[0] + o2b[0];
  __syncthreads();
  #pragma unroll
  for (int j = 0; j < CDIM; ++j) {
    red[c] = tr[c] * childw[j * E + c];
    __syncthreads();
    for (int s = 128; s > 0; s >>= 1) {
      if (c < s) red[c] += red[c + s];
      __syncthreads();
    }
    if (c == 0) out_child[r * CDIM + j] = red[0] + childb[j];
    __syncthreads();
  }
}

__global__ void rowdot_kernel(const float* __restrict__ A, const float* __restrict__ w,
                              const float* __restrict__ bias, float* __restrict__ out) {
  int r = blockIdx.x, l = threadIdx.x;
  const float* p = A + (size_t)r * E;
  float s = p[l] * w[l] + p[l + 64] * w[l + 64] + p[l + 128] * w[l + 128] + p[l + 192] * w[l + 192];
  for (int off = 32; off > 0; off >>= 1) s += __shfl_xor(s, off);
  if (l == 0) out[r] = s + bias[0];
}

extern "C" void kernel_launch(void* const* d_in, const int* in_sizes, int n_in,
                              void* d_out, int out_size, void* d_ws, size_t ws_size,
                              hipStream_t stream) {
  const float* x          = (const float*)d_in[0];
  const int*   parent_idx = (const int*)d_in[2];
  const float* in_w  = (const float*)d_in[3];
  const float* in_b  = (const float*)d_in[4];
  const float* bn_w  = (const float*)d_in[5];
  const float* bn_b  = (const float*)d_in[6];
  const float* dr_gamma = (const float*)d_in[7];
  const float* e_qkv_w = (const float*)d_in[8];
  const float* e_qkv_b = (const float*)d_in[9];
  const float* e_out_w = (const float*)d_in[10];
  const float* e_out_b = (const float*)d_in[11];
  const float* e_l1_w = (const float*)d_in[12];
  const float* e_l1_b = (const float*)d_in[13];
  const float* e_l2_w = (const float*)d_in[14];
  const float* e_l2_b = (const float*)d_in[15];
  const float* e_n1_w = (const float*)d_in[16];
  const float* e_n1_b = (const float*)d_in[17];
  const float* e_n2_w = (const float*)d_in[18];
  const float* e_n2_b = (const float*)d_in[19];
  const float* parent_w = (const float*)d_in[20];
  const float* parent_b = (const float*)d_in[21];
  const float* query_embed = (const float*)d_in[22];
  const float* c1_w = (const float*)d_in[23];
  const float* c1_b = (const float*)d_in[24];
  const float* c2_w = (const float*)d_in[25];
  const float* c2_b = (const float*)d_in[26];
  const float* d_sqkv_w = (const float*)d_in[27];
  const float* d_sqkv_b = (const float*)d_in[28];
  const float* d_sout_w = (const float*)d_in[29];
  const float* d_sout_b = (const float*)d_in[30];
  const float* d_cqkv_w = (const float*)d_in[31];
  const float* d_cqkv_b = (const float*)d_in[32];
  const float* d_cout_w = (const float*)d_in[33];
  const float* d_cout_b = (const float*)d_in[34];
  const float* d_l1_w = (const float*)d_in[35];
  const float* d_l1_b = (const float*)d_in[36];
  const float* d_l2_w = (const float*)d_in[37];
  const float* d_l2_b = (const float*)d_in[38];
  const float* d_n1_w = (const float*)d_in[39];
  const float* d_n1_b = (const float*)d_in[40];
  const float* d_n2_w = (const float*)d_in[41];
  const float* d_n2_b = (const float*)d_in[42];
  const float* d_n3_w = (const float*)d_in[43];
  const float* d_n3_b = (const float*)d_in[44];
  const float* child_w = (const float*)d_in[45];
  const float* child_b = (const float*)d_in[46];
  const float* o1_w = (const float*)d_in[47];
  const float* o1_b = (const float*)d_in[48];
  const float* o2_w = (const float*)d_in[49];
  const float* o2_b = (const float*)d_in[50];

  float* out = (float*)d_out;
  const int ROWS = BATCH * SEQ;
  const int TROWS = BATCH * KQ;

  // ---- workspace layout ----
  float* ws = (float*)d_ws;
  float* h         = ws;                                   // ROWS*E
  float* attnout_d = h + (size_t)ROWS * E;                 // TROWS*E
  float* pg        = attnout_d + (size_t)TROWS * E;        // B*2E
  float* tbuf      = pg + BATCH * 2 * E;                   // TROWS*E
  float* qkv_t     = tbuf + (size_t)TROWS * E;             // TROWS*3E
  float* dmid      = qkv_t + (size_t)TROWS * 3 * E;        // TROWS*FF
  float* kvb3      = dmid + (size_t)TROWS * FF;            // 1536
  unsigned short* kv_bf   = (unsigned short*)(kvb3 + 1536);  // ROWS*1536 bf16
  unsigned short* hn_bf   = kv_bf + (size_t)ROWS * 1536;   // ROWS*E
  unsigned short* attn_bf = hn_bf + (size_t)ROWS * E;      // ROWS*E
  unsigned short* mid_bf  = attn_bf + (size_t)ROWS * E;    // ROWS*FF
  unsigned short* eqkv_bf = mid_bf + (size_t)ROWS * FF;
  unsigned short* eout_bf = eqkv_bf + (size_t)LE * 3 * E * E;
  unsigned short* el1_bf  = eout_bf + (size_t)LE * E * E;
  unsigned short* el2_bf  = el1_bf + (size_t)LE * FF * E;
  unsigned short* kvw_bf  = el2_bf + (size_t)LE * E * FF;
  float2* carr = (float2*)(kvw_bf + (size_t)1536 * 256);
  unsigned short* qkb = mid_bf;
  unsigned short* vtb = mid_bf + (size_t)2 * ROWS * E;

  {
    const int total_quads = (LE * 3 * E * E + LE * E * E + LE * FF * E + LE * E * FF) / 4;
    cvt_all_kernel<<<(total_quads + 255) / 256, 256, 0, stream>>>(
        e_qkv_w, e_out_w, e_l1_w, e_l2_w, eqkv_bf, eout_bf, el1_bf, el2_bf);
  }
  kvw_remap_kernel<<<384, 256, 0, stream>>>(d_cqkv_w, d_cqkv_b, kvw_bf, kvb3);
  coords_kernel<<<(BATCH * SEQ + 255) / 256, 256, 0, stream>>>(x, carr);

  // input proj + layer0 ln1 fused
  input_proj_ln_kernel<<<ROWS, 256, 0, stream>>>(x, in_w, in_b, bn_w, bn_b,
                                                 e_n1_w, e_n1_b, h, hn_bf);

  // ---- encoder ----
  for (int i = 0; i < LE; ++i) {
    const float* qb = e_qkv_b + (size_t)i * 3 * E;
    const float* ob = e_out_b + (size_t)i * E;
    const float* l1b = e_l1_b + (size_t)i * FF;
    const float* l2b = e_l2_b + (size_t)i * E;
    if (i > 0)
      ln_bf16_kernel<<<ROWS / 4, 256, 0, stream>>>(h, e_n1_w + i * E, e_n1_b + i * E, hn_bf);
    mfma_gemm64o_kernel<0, 2><<<dim3(6, 128), 256, 0, stream>>>(
        hn_bf, eqkv_bf + (size_t)i * 3 * E * E, qb, qkb, vtb, 3 * E, E);
    mfma_attn_kernel<<<dim3(SEQ / 64, H, BATCH), 256, 0, stream>>>(qkb, vtb, carr, dr_gamma, attn_bf);
    mfma_gemm32_kernel<0><<<dim3(2, 256), 256, 0, stream>>>(
        attn_bf, eout_bf + (size_t)i * E * E, ob, h, h, nullptr, ROWS, E, E);
    ln_bf16_kernel<<<ROWS / 4, 256, 0, stream>>>(h, e_n2_w + i * E, e_n2_b + i * E, hn_bf);
    mfma_gemm64o_kernel<1, 1><<<dim3(8, 128), 256, 0, stream>>>(
        hn_bf, el1_bf + (size_t)i * FF * E, l1b, mid_bf, nullptr, FF, E);
    if (i < LE - 1)
      mfma_gemm32_kernel<0><<<dim3(2, 256), 256, 0, stream>>>(
          mid_bf, el2_bf + (size_t)i * E * FF, l2b, h, h, nullptr, ROWS, E, FF);
    else
      mfma_gemm32_kernel<1><<<dim3(2, 256), 256, 0, stream>>>(
          mid_bf, el2_bf + (size_t)i * E * FF, l2b, h, h, hn_bf, ROWS, E, FF);
  }
  // h == memory (fp32); hn_bf == bf16(memory)

  rowdot_kernel<<<ROWS, 64, 0, stream>>>(h, parent_w, parent_b, out);

  pool_gather_kernel<<<dim3(BATCH, 8), 256, 0, stream>>>(h, parent_idx, pg);
  cond_kernel<<<BATCH, 256, 0, stream>>>(pg, c1_w, c1_b, c2_w, c2_b, query_embed, tbuf);

  // ALL decoder KV projections in one GEMM (N=1536, bf16 out)
  mfma_gemm64o_kernel<0, 1><<<dim3(12, 128), 256, 0, stream>>>(
      hn_bf, kvw_bf, kvb3, kv_bf, nullptr, 3 * E * 2, E);

  // ---- decoder ----
  for (int i = 0; i < LDN; ++i) {
    dec_ln_gemv_kernel<768, 0><<<dim3(BATCH, 12), 256, 0, stream>>>(
        tbuf, d_n1_w + i * E, d_n1_b + i * E,
        d_sqkv_w + (size_t)i * 3 * E * E, d_sqkv_b + (size_t)i * 3 * E, qkv_t);
    dec_selfattn_sout_kernel<<<dim3(BATCH, 4), 256, 0, stream>>>(
        qkv_t, d_sout_w + (size_t)i * E * E, d_sout_b + (size_t)i * E, tbuf);
    cross_attn_ln_kernel<<<BATCH * H * KQ, 256, 0, stream>>>(
        tbuf, d_n2_w + i * E, d_n2_b + i * E,
        d_cqkv_w + (size_t)i * 3 * E * E, d_cqkv_b + (size_t)i * 3 * E,
        kv_bf, i * 512, i * 512 + 256, attnout_d);
    dec_gemv_resid_kernel<<<dim3(BATCH, 4), 256, 0, stream>>>(
        attnout_d, d_cout_w + (size_t)i * E * E, d_cout_b + (size_t)i * E, tbuf);
    dec_ln_gemv_kernel<1024, 1><<<dim3(BATCH, 16), 256, 0, stream>>>(
        tbuf, d_n3_w + i * E, d_n3_b + i * E,
        d_l1_w + (size_t)i * FF * E, d_l1_b + (size_t)i * FF, dmid);
    dec_ffn2_kernel<<<dim3(BATCH, 4), 256, 0, stream>>>(
        dmid, d_l2_w + (size_t)i * E * FF, d_l2_b + (size_t)i * E, tbuf);
  }

  // heads
  head_kernel<<<TROWS, 256, 0, stream>>>(tbuf, child_w, child_b, o1_w, o1_b, o2_w, o2_b,
                                         out + ROWS, out + ROWS + TROWS * CDIM);
}

// Round 17
// 744.198 us; speedup vs baseline: 1.0826x; 1.0826x over previous
//
#include <hip/hip_runtime.h>
#include <math.h>

#define E 256
#define H 8
#define HD 32
#define FF 1024
#define LE 4
#define LDN 3
#define KQ 8
#define CDIM 4
#define DIN 4
#define BATCH 16
#define SEQ 512

typedef __attribute__((ext_vector_type(8))) short s8b;
typedef __attribute__((ext_vector_type(4))) float f32x4;

__device__ __forceinline__ float gelu_f(float x) {
  return 0.5f * x * (1.f + erff(x * 0.70710678118654752f));
}

__device__ __forceinline__ unsigned short f2b(float f) {
  union { float f; unsigned u; } a;
  a.f = f;
  unsigned r = (a.u + 0x7fffu + ((a.u >> 16) & 1u)) >> 16;
  return (unsigned short)r;
}

__device__ __forceinline__ float b2f(unsigned short u) {
  union { unsigned u; float f; } a;
  a.u = ((unsigned)u) << 16;
  return a.f;
}

__device__ __forceinline__ void gload16(const unsigned short* g, unsigned short* l) {
  __builtin_amdgcn_global_load_lds((const __attribute__((address_space(1))) void*)g,
                                   (__attribute__((address_space(3))) void*)l, 16, 0, 0);
}

// ---------------- bf16 MFMA GEMM 64x128 tile, bf16/QKV-split output ----------------
// OMODE: 1 = bf16 row-major, 2 = QKV split (headmajor Q,K + transposed V)
template <int GELU, int OMODE>
__global__ __launch_bounds__(256) void mfma_gemm64o_kernel(
    const unsigned short* __restrict__ A, const unsigned short* __restrict__ Wt,
    const float* __restrict__ bias, unsigned short* __restrict__ outb,
    unsigned short* __restrict__ vtb, int N, int K) {
  __shared__ __align__(16) unsigned short As[64 * 32];
  __shared__ __align__(16) unsigned short Bs[128 * 32];
  int tid = threadIdx.x;
  int lane = tid & 63, w = tid >> 6;
  int row0 = blockIdx.y * 64, col0 = blockIdx.x * 128;
  int wr = (w >> 1) * 32, wc = (w & 1) * 64;
  f32x4 acc[2][4] = {};

  int sc = lane & 3;
  int srA = w * 16 + (lane >> 2);
  int gcA = (sc ^ ((srA >> 1) & 3)) * 8;
  const unsigned short* ApA = A + (size_t)(row0 + srA) * K + gcA;
  unsigned short* lA = As + (w * 16) * 32;
  int sr0 = w * 32 + (lane >> 2);
  int sr1 = sr0 + 16;
  int gc0 = (sc ^ ((sr0 >> 1) & 3)) * 8;
  int gc1 = (sc ^ ((sr1 >> 1) & 3)) * 8;
  const unsigned short* Bp0 = Wt + (size_t)(col0 + sr0) * K + gc0;
  const unsigned short* Bp1 = Wt + (size_t)(col0 + sr1) * K + gc1;
  unsigned short* lB0 = Bs + (w * 32) * 32;
  unsigned short* lB1 = Bs + (w * 32 + 16) * 32;

  for (int k0 = 0; k0 < K; k0 += 32) {
    __syncthreads();
    gload16(ApA + k0, lA);
    gload16(Bp0 + k0, lB0);
    gload16(Bp1 + k0, lB1);
    __syncthreads();
    int krow = lane & 15, kq = lane >> 4;
    s8b afr[2], bfr[4];
    #pragma unroll
    for (int mi = 0; mi < 2; ++mi) {
      int r = wr + mi * 16 + krow;
      afr[mi] = *(const s8b*)(As + r * 32 + ((kq ^ ((r >> 1) & 3)) * 8));
    }
    #pragma unroll
    for (int ni = 0; ni < 4; ++ni) {
      int r = wc + ni * 16 + krow;
      bfr[ni] = *(const s8b*)(Bs + r * 32 + ((kq ^ ((r >> 1) & 3)) * 8));
    }
    #pragma unroll
    for (int mi = 0; mi < 2; ++mi)
      #pragma unroll
      for (int ni = 0; ni < 4; ++ni)
        acc[mi][ni] = __builtin_amdgcn_mfma_f32_16x16x32_bf16(afr[mi], bfr[ni], acc[mi][ni], 0, 0, 0);
  }

  int cl = lane & 15, rb = (lane >> 4) * 4;
  #pragma unroll
  for (int ni = 0; ni < 4; ++ni) {
    int col = col0 + wc + ni * 16 + cl;
    float bv = bias[col];
    #pragma unroll
    for (int mi = 0; mi < 2; ++mi) {
      #pragma unroll
      for (int j = 0; j < 4; ++j) {
        int row = row0 + wr + mi * 16 + rb + j;
        float v = acc[mi][ni][j] + bv;
        if (GELU) v = gelu_f(v);
        if (OMODE == 1) {
          outb[(size_t)row * N + col] = f2b(v);
        } else {
          int b = row >> 9, s = row & 511;
          int sect = col >> 8, hh = (col >> 5) & 7, d = col & 31;
          if (sect < 2)
            outb[((((size_t)sect * BATCH + b) * H + hh) * SEQ + s) * HD + d] = f2b(v);
          else
            vtb[(((size_t)b * H + hh) * HD + d) * SEQ + s] = f2b(v);
        }
      }
    }
  }
}

// ---------------- bf16 MFMA GEMM 32x128 tile, fp32 out + bias + resid (+opt bf16 mirror) ----
template <int BF16OUT>
__global__ __launch_bounds__(256) void mfma_gemm32_kernel(
    const unsigned short* __restrict__ A, const unsigned short* __restrict__ Wt,
    const float* __restrict__ bias, const float* __restrict__ resid,
    float* __restrict__ outf, unsigned short* __restrict__ outb, int M, int N, int K) {
  __shared__ __align__(16) unsigned short As[32 * 32];
  __shared__ __align__(16) unsigned short Bs[128 * 32];
  int tid = threadIdx.x;
  int lane = tid & 63, w = tid >> 6;
  int row0 = blockIdx.y * 32, col0 = blockIdx.x * 128;
  int wr = (w & 1) * 16, wc = (w >> 1) * 64;
  f32x4 acc[4] = {};

  int sc = lane & 3;
  int srA = w * 16 + (lane >> 2);
  int gcA = (sc ^ ((srA >> 1) & 3)) * 8;
  const unsigned short* ApA = A + (size_t)(row0 + (srA & 31)) * K + gcA;
  unsigned short* lA = As + ((w & 1) * 16) * 32;
  int sr0 = w * 32 + (lane >> 2);
  int sr1 = sr0 + 16;
  int gc0 = (sc ^ ((sr0 >> 1) & 3)) * 8;
  int gc1 = (sc ^ ((sr1 >> 1) & 3)) * 8;
  const unsigned short* Bp0 = Wt + (size_t)(col0 + sr0) * K + gc0;
  const unsigned short* Bp1 = Wt + (size_t)(col0 + sr1) * K + gc1;
  unsigned short* lB0 = Bs + (w * 32) * 32;
  unsigned short* lB1 = Bs + (w * 32 + 16) * 32;

  for (int k0 = 0; k0 < K; k0 += 32) {
    __syncthreads();
    if (w < 2) gload16(ApA + k0, lA);
    gload16(Bp0 + k0, lB0);
    gload16(Bp1 + k0, lB1);
    __syncthreads();
    int krow = lane & 15, kq = lane >> 4;
    int ra = wr + krow;
    s8b afr = *(const s8b*)(As + ra * 32 + ((kq ^ ((ra >> 1) & 3)) * 8));
    #pragma unroll
    for (int ni = 0; ni < 4; ++ni) {
      int r = wc + ni * 16 + krow;
      s8b bfr = *(const s8b*)(Bs + r * 32 + ((kq ^ ((r >> 1) & 3)) * 8));
      acc[ni] = __builtin_amdgcn_mfma_f32_16x16x32_bf16(afr, bfr, acc[ni], 0, 0, 0);
    }
  }

  int cl = lane & 15, rb = (lane >> 4) * 4;
  #pragma unroll
  for (int ni = 0; ni < 4; ++ni) {
    int col = col0 + wc + ni * 16 + cl;
    float bv = bias[col];
    #pragma unroll
    for (int j = 0; j < 4; ++j) {
      int row = row0 + wr + rb + j;
      float v = acc[ni][j] + bv + resid[(size_t)row * N + col];
      outf[(size_t)row * N + col] = v;
      if (BF16OUT) outb[(size_t)row * N + col] = f2b(v);
    }
  }
}

// ---------------- MFMA encoder attention ----------------
__global__ __launch_bounds__(256) void mfma_attn_kernel(
    const unsigned short* __restrict__ qkb, const unsigned short* __restrict__ vt,
    const float2* __restrict__ carr, const float* __restrict__ gamma_p,
    unsigned short* __restrict__ out) {
  __shared__ __align__(16) unsigned short P[4][16 * 64];
  int tid = threadIdx.x, lane = tid & 63, w = tid >> 6;
  int qt = blockIdx.x, h = blockIdx.y, b = blockIdx.z;
  int q0 = qt * 64 + w * 16;
  const unsigned short* qh = qkb + (((size_t)b * H + h) * SEQ) * HD;
  const unsigned short* kh = qkb + ((((size_t)BATCH + b) * H + h) * SEQ) * HD;
  const unsigned short* vh = vt + (((size_t)b * H + h) * HD) * SEQ;
  int r16 = lane & 15, q4 = lane >> 4;
  s8b qa = *(const s8b*)(qh + (size_t)(q0 + r16) * HD + q4 * 8);
  float eq[4], pq[4];
  #pragma unroll
  for (int j = 0; j < 4; ++j) {
    float2 c = carr[b * SEQ + q0 + q4 * 4 + j];
    eq[j] = c.x; pq[j] = c.y;
  }
  float gam = gamma_p[0] * 0.49999999500000004f;
  const float scale = 0.17677669529663687f;
  float m[4], lsum[4];
  #pragma unroll
  for (int j = 0; j < 4; ++j) { m[j] = -1e30f; lsum[j] = 0.f; }
  f32x4 o0 = {}, o1 = {};
  const f32x4 zf = {0.f, 0.f, 0.f, 0.f};
  unsigned short* pw = &P[w][0];

  for (int t = 0; t < SEQ / 64; ++t) {
    int k0 = t * 64;
    f32x4 sf[4];
    #pragma unroll
    for (int f = 0; f < 4; ++f) {
      s8b bk = *(const s8b*)(kh + (size_t)(k0 + f * 16 + r16) * HD + q4 * 8);
      sf[f] = __builtin_amdgcn_mfma_f32_16x16x32_bf16(qa, bk, zf, 0, 0, 0);
    }
    float ek[4], pk[4];
    #pragma unroll
    for (int f = 0; f < 4; ++f) {
      float2 c = carr[b * SEQ + k0 + f * 16 + r16];
      ek[f] = c.x; pk[f] = c.y;
    }
    float sc_[4][4];
    float tmax[4] = {-1e30f, -1e30f, -1e30f, -1e30f};
    #pragma unroll
    for (int f = 0; f < 4; ++f)
      #pragma unroll
      for (int j = 0; j < 4; ++j) {
        float de = eq[j] - ek[f], dp = pq[j] - pk[f];
        float v = sf[f][j] * scale - gam * (de * de + dp * dp);
        sc_[f][j] = v;
        tmax[j] = fmaxf(tmax[j], v);
      }
    #pragma unroll
    for (int j = 0; j < 4; ++j) {
      #pragma unroll
      for (int off = 1; off < 16; off <<= 1)
        tmax[j] = fmaxf(tmax[j], __shfl_xor(tmax[j], off));
      float mn = fmaxf(m[j], tmax[j]);
      float al = __expf(m[j] - mn);
      m[j] = mn;
      lsum[j] *= al;
      o0[j] *= al;
      o1[j] *= al;
    }
    __syncthreads();
    #pragma unroll
    for (int f = 0; f < 4; ++f)
      #pragma unroll
      for (int j = 0; j < 4; ++j) {
        float p = __expf(sc_[f][j] - m[j]);
        lsum[j] += p;
        int prow = q4 * 4 + j;
        int c = f * 16 + r16;
        int chunk = (c >> 3) ^ (prow & 7);
        pw[prow * 64 + chunk * 8 + (c & 7)] = f2b(p);
      }
    __syncthreads();
    #pragma unroll
    for (int ks = 0; ks < 2; ++ks) {
      int chunk = (ks * 4 + q4) ^ (r16 & 7);
      s8b pa = *(const s8b*)(pw + r16 * 64 + chunk * 8);
      s8b v0 = *(const s8b*)(vh + (size_t)r16 * SEQ + k0 + ks * 32 + q4 * 8);
      s8b v1 = *(const s8b*)(vh + (size_t)(16 + r16) * SEQ + k0 + ks * 32 + q4 * 8);
      o0 = __builtin_amdgcn_mfma_f32_16x16x32_bf16(pa, v0, o0, 0, 0, 0);
      o1 = __builtin_amdgcn_mfma_f32_16x16x32_bf16(pa, v1, o1, 0, 0, 0);
    }
  }
  #pragma unroll
  for (int j = 0; j < 4; ++j) {
    #pragma unroll
    for (int off = 1; off < 16; off <<= 1)
      lsum[j] += __shfl_xor(lsum[j], off);
    float inv = 1.f / lsum[j];
    size_t rbase = ((size_t)(b * SEQ + q0 + q4 * 4 + j)) * E + h * HD;
    out[rbase + r16] = f2b(o0[j] * inv);
    out[rbase + 16 + r16] = f2b(o1[j] * inv);
  }
}

__global__ void coords_kernel(const float* __restrict__ x, float2* __restrict__ carr) {
  int i = blockIdx.x * 256 + threadIdx.x;
  if (i >= BATCH * SEQ) return;
  carr[i] = make_float2(x[(size_t)i * DIN + 1], x[(size_t)i * DIN + 2]);
}

// merged conversion of the 4 encoder weight tensors
__global__ void cvt_all_kernel(const float* __restrict__ w0, const float* __restrict__ w1,
                               const float* __restrict__ w2, const float* __restrict__ w3,
                               unsigned short* __restrict__ o0, unsigned short* __restrict__ o1,
                               unsigned short* __restrict__ o2, unsigned short* __restrict__ o3) {
  const int n0 = LE * 3 * E * E / 4, n1 = LE * E * E / 4;
  const int n2 = LE * FF * E / 4, n3 = LE * E * FF / 4;
  int j = blockIdx.x * 256 + threadIdx.x;
  const float* src; unsigned short* dst;
  if (j < n0) { src = w0; dst = o0; }
  else if ((j -= n0) < n1) { src = w1; dst = o1; }
  else if ((j -= n1) < n2) { src = w2; dst = o2; }
  else if ((j -= n2) < n3) { src = w3; dst = o3; }
  else return;
  float4 v = ((const float4*)src)[j];
  ushort4 o;
  o.x = f2b(v.x); o.y = f2b(v.y); o.z = f2b(v.z); o.w = f2b(v.w);
  ((ushort4*)dst)[j] = o;
}

// remap decoder KV weights [LDN][3E][E] -> combined [3*512][256] bf16 + bias [1536]
__global__ void kvw_remap_kernel(const float* __restrict__ w, const float* __restrict__ b,
                                 unsigned short* __restrict__ wout, float* __restrict__ bout) {
  int i = blockIdx.x * 256 + threadIdx.x;
  if (i < 1536) bout[i] = b[(i >> 9) * 768 + 256 + (i & 511)];
  if (i >= 98304) return;
  int row = i >> 6, cc = i & 63;
  int l = row >> 9, rr = row & 511;
  const float* src = w + ((size_t)l * 768 + 256 + rr) * 256 + cc * 4;
  float4 v = *(const float4*)src;
  ushort4 o;
  o.x = f2b(v.x); o.y = f2b(v.y); o.z = f2b(v.z); o.w = f2b(v.w);
  *(ushort4*)(wout + (size_t)row * 256 + cc * 4) = o;
}

// input_proj + BN(eval) + GELU + layer0 ln1, writing h (fp32) and hn (bf16 LN'd)
__global__ __launch_bounds__(256) void input_proj_ln_kernel(
    const float* __restrict__ x, const float* __restrict__ in_w, const float* __restrict__ in_b,
    const float* __restrict__ bn_w, const float* __restrict__ bn_b,
    const float* __restrict__ nw, const float* __restrict__ nb,
    float* __restrict__ h, unsigned short* __restrict__ hn) {
  __shared__ float sred[4];
  __shared__ float vred[4];
  int row = blockIdx.x, e = threadIdx.x;
  const float* xr = x + (size_t)row * DIN;
  float v = in_b[e];
  #pragma unroll
  for (int i = 0; i < DIN; ++i) v += xr[i] * in_w[e * DIN + i];
  v = v * (1.0f / sqrtf(1.0f + 1e-5f)) * bn_w[e] + bn_b[e];
  v = gelu_f(v);
  h[(size_t)row * 256 + e] = v;
  int lane = e & 63, w = e >> 6;
  float s = v;
  #pragma unroll
  for (int off = 32; off > 0; off >>= 1) s += __shfl_xor(s, off);
  if (lane == 0) sred[w] = s;
  __syncthreads();
  float mean = (sred[0] + sred[1] + sred[2] + sred[3]) * (1.f / 256);
  float d = v - mean;
  float vr = d * d;
  #pragma unroll
  for (int off = 32; off > 0; off >>= 1) vr += __shfl_xor(vr, off);
  if (lane == 0) vred[w] = vr;
  __syncthreads();
  float inv = rsqrtf((vred[0] + vred[1] + vred[2] + vred[3]) * (1.f / 256) + 1e-5f);
  hn[(size_t)row * 256 + e] = f2b(d * inv * nw[e] + nb[e]);
}

// 4 rows per block (256 threads, wave per row)
__global__ __launch_bounds__(256) void ln_bf16_kernel(
    const float* __restrict__ in, const float* __restrict__ w,
    const float* __restrict__ b, unsigned short* __restrict__ out) {
  int r = blockIdx.x * 4 + (threadIdx.x >> 6);
  int l = threadIdx.x & 63;
  const float* p = in + (size_t)r * E;
  float v0 = p[l], v1 = p[l + 64], v2 = p[l + 128], v3 = p[l + 192];
  float s = v0 + v1 + v2 + v3;
  for (int off = 32; off > 0; off >>= 1) s += __shfl_xor(s, off);
  float mean = s * (1.f / E);
  float d0 = v0 - mean, d1 = v1 - mean, d2 = v2 - mean, d3 = v3 - mean;
  float var = d0 * d0 + d1 * d1 + d2 * d2 + d3 * d3;
  for (int off = 32; off > 0; off >>= 1) var += __shfl_xor(var, off);
  float inv = rsqrtf(var * (1.f / E) + 1e-5f);
  unsigned short* o = out + (size_t)r * E;
  o[l]       = f2b(d0 * inv * w[l]       + b[l]);
  o[l + 64]  = f2b(d1 * inv * w[l + 64]  + b[l + 64]);
  o[l + 128] = f2b(d2 * inv * w[l + 128] + b[l + 128]);
  o[l + 192] = f2b(d3 * inv * w[l + 192] + b[l + 192]);
}

// ========== decoder stage kernels ==========

template <int N, int GELU>
__global__ __launch_bounds__(256) void dec_ln_gemv_kernel(
    const float* __restrict__ t, const float* __restrict__ nw, const float* __restrict__ nb,
    const float* __restrict__ W, const float* __restrict__ bias, float* __restrict__ outg) {
  __shared__ float X[8][256];
  __shared__ float Pp[4][64][9];
  int b = blockIdx.x, by = blockIdx.y, tid = threadIdx.x;
  const float* tg = t + (size_t)b * 2048;
  int w = tid >> 6, l = tid & 63;
  #pragma unroll
  for (int rr = 0; rr < 2; ++rr) {
    int r = w * 2 + rr;
    float v0 = tg[r * 256 + l], v1 = tg[r * 256 + 64 + l];
    float v2 = tg[r * 256 + 128 + l], v3 = tg[r * 256 + 192 + l];
    float s = v0 + v1 + v2 + v3;
    for (int o = 32; o > 0; o >>= 1) s += __shfl_xor(s, o);
    float mean = s * (1.f / 256);
    float d0 = v0 - mean, d1 = v1 - mean, d2 = v2 - mean, d3 = v3 - mean;
    float var = d0 * d0 + d1 * d1 + d2 * d2 + d3 * d3;
    for (int o = 32; o > 0; o >>= 1) var += __shfl_xor(var, o);
    float inv = rsqrtf(var * (1.f / 256) + 1e-5f);
    X[r][l] = d0 * inv * nw[l] + nb[l];
    X[r][l + 64] = d1 * inv * nw[l + 64] + nb[l + 64];
    X[r][l + 128] = d2 * inv * nw[l + 128] + nb[l + 128];
    X[r][l + 192] = d3 * inv * nw[l + 192] + nb[l + 192];
  }
  __syncthreads();
  int j = tid & 63, kq = tid >> 6;
  int col = by * 64 + j;
  const float4* wp = (const float4*)(W + (size_t)col * 256 + kq * 64);
  float acc[8] = {};
  #pragma unroll
  for (int kk = 0; kk < 16; ++kk) {
    float4 wv = wp[kk];
    int base = kq * 64 + kk * 4;
    #pragma unroll
    for (int r = 0; r < 8; ++r) {
      float4 xv = *(const float4*)&X[r][base];
      acc[r] += xv.x * wv.x + xv.y * wv.y + xv.z * wv.z + xv.w * wv.w;
    }
  }
  #pragma unroll
  for (int r = 0; r < 8; ++r) Pp[kq][j][r] = acc[r];
  __syncthreads();
  for (int i = tid; i < 512; i += 256) {
    int r = i & 7, j2 = i >> 3;
    float v = Pp[0][j2][r] + Pp[1][j2][r] + Pp[2][j2][r] + Pp[3][j2][r] + bias[by * 64 + j2];
    if (GELU) v = gelu_f(v);
    outg[((size_t)b * 8 + r) * N + by * 64 + j2] = v;
  }
}

// fused: self-attention (recomputed per col-block) + sout GEMV chunk + resid into t
__global__ __launch_bounds__(256) void dec_selfattn_sout_kernel(
    const float* __restrict__ qkvg, const float* __restrict__ W, const float* __restrict__ bias,
    float* __restrict__ t) {
  __shared__ float QK[8][768];
  __shared__ float S[512];
  __shared__ float X[8][256];
  __shared__ float Pp[4][64][9];
  int b = blockIdx.x, by = blockIdx.y, tid = threadIdx.x;
  const float* qg = qkvg + (size_t)b * 8 * 768;
  for (int i = tid; i < 6144; i += 256) ((float*)QK)[i] = qg[i];
  __syncthreads();
  for (int t2 = tid; t2 < 512; t2 += 256) {
    int h = t2 >> 6, q = (t2 >> 3) & 7, k = t2 & 7;
    const float* qp = &QK[q][h * 32];
    const float* kp = &QK[k][256 + h * 32];
    float d = 0.f;
    #pragma unroll
    for (int jj = 0; jj < 32; ++jj) d += qp[jj] * kp[jj];
    S[t2] = d * 0.17677669529663687f;
  }
  __syncthreads();
  if (tid < 64) {
    float* row = &S[tid * 8];
    float m = row[0];
    #pragma unroll
    for (int k = 1; k < 8; ++k) m = fmaxf(m, row[k]);
    float sum = 0.f;
    #pragma unroll
    for (int k = 0; k < 8; ++k) { float e = __expf(row[k] - m); row[k] = e; sum += e; }
    float inv = 1.f / sum;
    #pragma unroll
    for (int k = 0; k < 8; ++k) row[k] *= inv;
  }
  __syncthreads();
  for (int i = tid; i < 2048; i += 256) {
    int q = i >> 8, c = i & 255, h = c >> 5;
    const float* pr = &S[h * 64 + q * 8];
    float acc = 0.f;
    #pragma unroll
    for (int k = 0; k < 8; ++k) acc += pr[k] * QK[k][512 + c];
    X[q][c] = acc;
  }
  __syncthreads();
  int j = tid & 63, kq = tid >> 6;
  int col = by * 64 + j;
  const float4* wp = (const float4*)(W + (size_t)col * 256 + kq * 64);
  float acc[8] = {};
  #pragma unroll
  for (int kk = 0; kk < 16; ++kk) {
    float4 wv = wp[kk];
    int base = kq * 64 + kk * 4;
    #pragma unroll
    for (int r = 0; r < 8; ++r) {
      float4 xv = *(const float4*)&X[r][base];
      acc[r] += xv.x * wv.x + xv.y * wv.y + xv.z * wv.z + xv.w * wv.w;
    }
  }
  #pragma unroll
  for (int r = 0; r < 8; ++r) Pp[kq][j][r] = acc[r];
  __syncthreads();
  for (int i = tid; i < 512; i += 256) {
    int r = i & 7, j2 = i >> 3;
    float v = Pp[0][j2][r] + Pp[1][j2][r] + Pp[2][j2][r] + Pp[3][j2][r] + bias[by * 64 + j2];
    t[((size_t)b * 8 + r) * 256 + by * 64 + j2] += v;
  }
}

__global__ __launch_bounds__(256) void dec_gemv_resid_kernel(
    const float* __restrict__ Xg, const float* __restrict__ W, const float* __restrict__ bias,
    float* __restrict__ t) {
  __shared__ float X[8][256];
  __shared__ float Pp[4][64][9];
  int b = blockIdx.x, by = blockIdx.y, tid = threadIdx.x;
  const float* xg = Xg + (size_t)b * 2048;
  for (int i = tid; i < 2048; i += 256) ((float*)X)[i] = xg[i];
  __syncthreads();
  int j = tid & 63, kq = tid >> 6;
  int col = by * 64 + j;
  const float4* wp = (const float4*)(W + (size_t)col * 256 + kq * 64);
  float acc[8] = {};
  #pragma unroll
  for (int kk = 0; kk < 16; ++kk) {
    float4 wv = wp[kk];
    int base = kq * 64 + kk * 4;
    #pragma unroll
    for (int r = 0; r < 8; ++r) {
      float4 xv = *(const float4*)&X[r][base];
      acc[r] += xv.x * wv.x + xv.y * wv.y + xv.z * wv.z + xv.w * wv.w;
    }
  }
  #pragma unroll
  for (int r = 0; r < 8; ++r) Pp[kq][j][r] = acc[r];
  __syncthreads();
  for (int i = tid; i < 512; i += 256) {
    int r = i & 7, j2 = i >> 3;
    float v = Pp[0][j2][r] + Pp[1][j2][r] + Pp[2][j2][r] + Pp[3][j2][r] + bias[by * 64 + j2];
    t[((size_t)b * 8 + r) * 256 + by * 64 + j2] += v;
  }
}

__global__ __launch_bounds__(256) void dec_ffn2_kernel(
    const float* __restrict__ MIDg, const float* __restrict__ W, const float* __restrict__ bias,
    float* __restrict__ t) {
  __shared__ float X[8][1024];
  __shared__ float Pp[4][64][9];
  int b = blockIdx.x, by = blockIdx.y, tid = threadIdx.x;
  const float* xg = MIDg + (size_t)b * 8192;
  for (int i = tid; i < 8192; i += 256) ((float*)X)[i] = xg[i];
  __syncthreads();
  int j = tid & 63, kq = tid >> 6;
  int col = by * 64 + j;
  const float4* wp = (const float4*)(W + (size_t)col * 1024 + kq * 256);
  float acc[8] = {};
  #pragma unroll 8
  for (int kk = 0; kk < 64; ++kk) {
    float4 wv = wp[kk];
    int base = kq * 256 + kk * 4;
    #pragma unroll
    for (int r = 0; r < 8; ++r) {
      float4 xv = *(const float4*)&X[r][base];
      acc[r] += xv.x * wv.x + xv.y * wv.y + xv.z * wv.z + xv.w * wv.w;
    }
  }
  #pragma unroll
  for (int r = 0; r < 8; ++r) Pp[kq][j][r] = acc[r];
  __syncthreads();
  for (int i = tid; i < 512; i += 256) {
    int r = i & 7, j2 = i >> 3;
    float v = Pp[0][j2][r] + Pp[1][j2][r] + Pp[2][j2][r] + Pp[3][j2][r] + bias[by * 64 + j2];
    t[((size_t)b * 8 + r) * 256 + by * 64 + j2] += v;
  }
}

// cross attention with fused ln2 + Q-projection: one block per (b,h,q) over bf16 KV
__global__ __launch_bounds__(256) void cross_attn_ln_kernel(
    const float* __restrict__ t, const float* __restrict__ nw, const float* __restrict__ nb,
    const float* __restrict__ cqw, const float* __restrict__ cqb,
    const unsigned short* __restrict__ KV, int koff, int voff, float* __restrict__ out) {
  __shared__ float X[256];
  __shared__ float sv[512];
  __shared__ float red[256];
  __shared__ float qv[32];
  __shared__ float pvred[8][32];
  __shared__ float sred[4], vred[4];
  int tid = threadIdx.x;
  int bid = blockIdx.x;
  int q = bid % KQ;
  int h = (bid / KQ) % H;
  int b = bid / (KQ * H);
  {
    float v = t[((size_t)(b * KQ + q)) * 256 + tid];
    int lane = tid & 63, w = tid >> 6;
    float s = v;
    #pragma unroll
    for (int off = 32; off > 0; off >>= 1) s += __shfl_xor(s, off);
    if (lane == 0) sred[w] = s;
    __syncthreads();
    float mean = (sred[0] + sred[1] + sred[2] + sred[3]) * (1.f / 256);
    float d = v - mean;
    float vr = d * d;
    #pragma unroll
    for (int off = 32; off > 0; off >>= 1) vr += __shfl_xor(vr, off);
    if (lane == 0) vred[w] = vr;
    __syncthreads();
    float inv = rsqrtf((vred[0] + vred[1] + vred[2] + vred[3]) * (1.f / 256) + 1e-5f);
    X[tid] = d * inv * nw[tid] + nb[tid];
  }
  __syncthreads();
  {
    int dd = tid >> 3, part = tid & 7;
    int col = h * HD + dd;
    const float4* wp = (const float4*)(cqw + (size_t)col * 256 + part * 32);
    float acc = 0.f;
    #pragma unroll
    for (int kk = 0; kk < 8; ++kk) {
      float4 wv = wp[kk];
      float4 xv = *(const float4*)&X[part * 32 + kk * 4];
      acc += xv.x * wv.x + xv.y * wv.y + xv.z * wv.z + xv.w * wv.w;
    }
    red[tid] = acc;
  }
  __syncthreads();
  if (tid < 32) {
    float acc = 0.f;
    #pragma unroll
    for (int p = 0; p < 8; ++p) acc += red[tid * 8 + p];
    qv[tid] = acc + cqb[h * HD + tid];
  }
  __syncthreads();
  const float scale = 0.17677669529663687f;
  for (int k = tid; k < SEQ; k += 256) {
    const unsigned short* kp = KV + ((size_t)(b * SEQ + k)) * 1536 + koff + h * HD;
    float d = 0.f;
    #pragma unroll
    for (int j4 = 0; j4 < 4; ++j4) {
      s8b kv8 = *(const s8b*)(kp + j4 * 8);
      #pragma unroll
      for (int j = 0; j < 8; ++j)
        d += qv[j4 * 8 + j] * b2f((unsigned short)kv8[j]);
    }
    sv[k] = d * scale;
  }
  __syncthreads();
  float m = -1e30f;
  for (int k = tid; k < SEQ; k += 256) m = fmaxf(m, sv[k]);
  red[tid] = m; __syncthreads();
  for (int s = 128; s > 0; s >>= 1) {
    if (tid < s) red[tid] = fmaxf(red[tid], red[tid + s]);
    __syncthreads();
  }
  m = red[0]; __syncthreads();
  float lsum = 0.f;
  for (int k = tid; k < SEQ; k += 256) { float e = __expf(sv[k] - m); sv[k] = e; lsum += e; }
  red[tid] = lsum; __syncthreads();
  for (int s = 128; s > 0; s >>= 1) {
    if (tid < s) red[tid] += red[tid + s];
    __syncthreads();
  }
  float denom = red[0];
  int d = tid & 31, g = tid >> 5;
  float acc = 0.f;
  for (int k = g; k < SEQ; k += 8)
    acc += sv[k] * b2f(KV[((size_t)(b * SEQ + k)) * 1536 + voff + h * HD + d]);
  pvred[g][d] = acc;
  __syncthreads();
  if (tid < 32) {
    float r = 0.f;
    #pragma unroll
    for (int gg = 0; gg < 8; ++gg) r += pvred[gg][tid];
    out[((size_t)(b * KQ + q)) * E + h * HD + tid] = r / denom;
  }
}

__global__ __launch_bounds__(256) void pool_gather_kernel(
    const float* __restrict__ mem, const int* __restrict__ pidx, float* __restrict__ pg) {
  __shared__ float red[8][32];
  int b = blockIdx.x, cy = blockIdx.y, tid = threadIdx.x;
  int c = cy * 32 + (tid & 31), g = tid >> 5;
  float s = 0.f;
  for (int r = g; r < SEQ; r += 8)
    s += mem[((size_t)b * SEQ + r) * E + c];
  red[g][tid & 31] = s;
  __syncthreads();
  if (tid < 32) {
    float t = 0.f;
    #pragma unroll
    for (int g2 = 0; g2 < 8; ++g2) t += red[g2][tid];
    pg[(size_t)b * 512 + 256 + cy * 32 + tid] = t * (1.f / SEQ);
    pg[(size_t)b * 512 + cy * 32 + tid] = mem[((size_t)b * SEQ + pidx[b]) * E + cy * 32 + tid];
  }
}

__global__ void cond_kernel(const float* __restrict__ pg, const float* __restrict__ c1w,
                            const float* __restrict__ c1b, const float* __restrict__ c2w,
                            const float* __restrict__ c2b, const float* __restrict__ qe,
                            float* __restrict__ t) {
  __shared__ float PG[512];
  __shared__ float C1[256];
  int b = blockIdx.x, c = threadIdx.x;
  PG[c] = pg[(size_t)b * 512 + c];
  PG[c + 256] = pg[(size_t)b * 512 + 256 + c];
  __syncthreads();
  const float4* wp = (const float4*)(c1w + (size_t)c * 512);
  float acc = c1b[c];
  #pragma unroll 8
  for (int kk = 0; kk < 128; ++kk) {
    float4 wv = wp[kk];
    int base = kk * 4;
    acc += PG[base] * wv.x + PG[base + 1] * wv.y + PG[base + 2] * wv.z + PG[base + 3] * wv.w;
  }
  C1[c] = gelu_f(acc);
  __syncthreads();
  const float4* wp2 = (const float4*)(c2w + (size_t)c * 256);
  float acc2 = c2b[c];
  #pragma unroll 8
  for (int kk = 0; kk < 64; ++kk) {
    float4 wv = wp2[kk];
    int base = kk * 4;
    acc2 += C1[base] * wv.x + C1[base + 1] * wv.y + C1[base + 2] * wv.z + C1[base + 3] * wv.w;
  }
  #pragma unroll
  for (int k = 0; k < KQ; ++k)
    t[((size_t)b * KQ + k) * E + c] = qe[k * E + c] + acc2;
}

__global__ void head_kernel(const float* __restrict__ t,
                            const float* __restrict__ childw, const float* __restrict__ childb,
                            const float* __restrict__ o1w, const float* __restrict__ o1b,
                            const float* __restrict__ o2w, const float* __restrict__ o2b,
                            float* __restrict__ out_child, float* __restrict__ out_obj) {
  __shared__ float tr[256];
  __shared__ float red[256];
  int r = blockIdx.x, c = threadIdx.x;
  tr[c] = t[(size_t)r * E + c];
  __syncthreads();
  const float4* wp = (const float4*)(o1w + (size_t)c * 256);
  float acc = o1b[c];
  #pragma unroll 8
  for (int kk = 0; kk < 64; ++kk) {
    float4 wv = wp[kk];
    int base = kk * 4;
    acc += tr[base] * wv.x + tr[base + 1] * wv.y + tr[base + 2] * wv.z + tr[base + 3] * wv.w;
  }
  red[c] = gelu_f(acc) * o2w[c];
  __syncthreads();
  for (int s = 128; s > 0; s >>= 1) {
    if (c < s) red[c] += red[c + s];
    __syncthreads();
  }
  if (c == 0) out_obj[r] = red[0] + o2b[0];
  __syncthreads();
  #pragma unroll
  for (int j = 0; j < CDIM; ++j) {
    red[c] = tr[c] * childw[j * E + c];
    __syncthreads();
    for (int s = 128; s > 0; s >>= 1) {
      if (c < s) red[c] += red[c + s];
      __syncthreads();
    }
    if (c == 0) out_child[r * CDIM + j] = red[0] + childb[j];
    __syncthreads();
  }
}

__global__ void rowdot_kernel(const float* __restrict__ A, const float* __restrict__ w,
                              const float* __restrict__ bias, float* __restrict__ out) {
  int r = blockIdx.x, l = threadIdx.x;
  const float* p = A + (size_t)r * E;
  float s = p[l] * w[l] + p[l + 64] * w[l + 64] + p[l + 128] * w[l + 128] + p[l + 192] * w[l + 192];
  for (int off = 32; off > 0; off >>= 1) s += __shfl_xor(s, off);
  if (l == 0) out[r] = s + bias[0];
}

extern "C" void kernel_launch(void* const* d_in, const int* in_sizes, int n_in,
                              void* d_out, int out_size, void* d_ws, size_t ws_size,
                              hipStream_t stream) {
  const float* x          = (const float*)d_in[0];
  const int*   parent_idx = (const int*)d_in[2];
  const float* in_w  = (const float*)d_in[3];
  const float* in_b  = (const float*)d_in[4];
  const float* bn_w  = (const float*)d_in[5];
  const float* bn_b  = (const float*)d_in[6];
  const float* dr_gamma = (const float*)d_in[7];
  const float* e_qkv_w = (const float*)d_in[8];
  const float* e_qkv_b = (const float*)d_in[9];
  const float* e_out_w = (const float*)d_in[10];
  const float* e_out_b = (const float*)d_in[11];
  const float* e_l1_w = (const float*)d_in[12];
  const float* e_l1_b = (const float*)d_in[13];
  const float* e_l2_w = (const float*)d_in[14];
  const float* e_l2_b = (const float*)d_in[15];
  const float* e_n1_w = (const float*)d_in[16];
  const float* e_n1_b = (const float*)d_in[17];
  const float* e_n2_w = (const float*)d_in[18];
  const float* e_n2_b = (const float*)d_in[19];
  const float* parent_w = (const float*)d_in[20];
  const float* parent_b = (const float*)d_in[21];
  const float* query_embed = (const float*)d_in[22];
  const float* c1_w = (const float*)d_in[23];
  const float* c1_b = (const float*)d_in[24];
  const float* c2_w = (const float*)d_in[25];
  const float* c2_b = (const float*)d_in[26];
  const float* d_sqkv_w = (const float*)d_in[27];
  const float* d_sqkv_b = (const float*)d_in[28];
  const float* d_sout_w = (const float*)d_in[29];
  const float* d_sout_b = (const float*)d_in[30];
  const float* d_cqkv_w = (const float*)d_in[31];
  const float* d_cqkv_b = (const float*)d_in[32];
  const float* d_cout_w = (const float*)d_in[33];
  const float* d_cout_b = (const float*)d_in[34];
  const float* d_l1_w = (const float*)d_in[35];
  const float* d_l1_b = (const float*)d_in[36];
  const float* d_l2_w = (const float*)d_in[37];
  const float* d_l2_b = (const float*)d_in[38];
  const float* d_n1_w = (const float*)d_in[39];
  const float* d_n1_b = (const float*)d_in[40];
  const float* d_n2_w = (const float*)d_in[41];
  const float* d_n2_b = (const float*)d_in[42];
  const float* d_n3_w = (const float*)d_in[43];
  const float* d_n3_b = (const float*)d_in[44];
  const float* child_w = (const float*)d_in[45];
  const float* child_b = (const float*)d_in[46];
  const float* o1_w = (const float*)d_in[47];
  const float* o1_b = (const float*)d_in[48];
  const float* o2_w = (const float*)d_in[49];
  const float* o2_b = (const float*)d_in[50];

  float* out = (float*)d_out;
  const int ROWS = BATCH * SEQ;
  const int TROWS = BATCH * KQ;

  // ---- workspace layout ----
  float* ws = (float*)d_ws;
  float* h         = ws;                                   // ROWS*E
  float* attnout_d = h + (size_t)ROWS * E;                 // TROWS*E
  float* pg        = attnout_d + (size_t)TROWS * E;        // B*2E
  float* tbuf      = pg + BATCH * 2 * E;                   // TROWS*E
  float* qkv_t     = tbuf + (size_t)TROWS * E;             // TROWS*3E
  float* dmid      = qkv_t + (size_t)TROWS * 3 * E;        // TROWS*FF
  float* kvb3      = dmid + (size_t)TROWS * FF;            // 1536
  unsigned short* kv_bf   = (unsigned short*)(kvb3 + 1536);  // ROWS*1536 bf16
  unsigned short* hn_bf   = kv_bf + (size_t)ROWS * 1536;   // ROWS*E
  unsigned short* attn_bf = hn_bf + (size_t)ROWS * E;      // ROWS*E
  unsigned short* mid_bf  = attn_bf + (size_t)ROWS * E;    // ROWS*FF
  unsigned short* eqkv_bf = mid_bf + (size_t)ROWS * FF;
  unsigned short* eout_bf = eqkv_bf + (size_t)LE * 3 * E * E;
  unsigned short* el1_bf  = eout_bf + (size_t)LE * E * E;
  unsigned short* el2_bf  = el1_bf + (size_t)LE * FF * E;
  unsigned short* kvw_bf  = el2_bf + (size_t)LE * E * FF;
  float2* carr = (float2*)(kvw_bf + (size_t)1536 * 256);
  unsigned short* qkb = mid_bf;
  unsigned short* vtb = mid_bf + (size_t)2 * ROWS * E;

  {
    const int total_quads = (LE * 3 * E * E + LE * E * E + LE * FF * E + LE * E * FF) / 4;
    cvt_all_kernel<<<(total_quads + 255) / 256, 256, 0, stream>>>(
        e_qkv_w, e_out_w, e_l1_w, e_l2_w, eqkv_bf, eout_bf, el1_bf, el2_bf);
  }
  kvw_remap_kernel<<<384, 256, 0, stream>>>(d_cqkv_w, d_cqkv_b, kvw_bf, kvb3);
  coords_kernel<<<(BATCH * SEQ + 255) / 256, 256, 0, stream>>>(x, carr);

  // input proj + layer0 ln1 fused
  input_proj_ln_kernel<<<ROWS, 256, 0, stream>>>(x, in_w, in_b, bn_w, bn_b,
                                                 e_n1_w, e_n1_b, h, hn_bf);

  // ---- encoder (round-13 structure; last FFN2 mirrors bf16 memory) ----
  for (int i = 0; i < LE; ++i) {
    const float* qb = e_qkv_b + (size_t)i * 3 * E;
    const float* ob = e_out_b + (size_t)i * E;
    const float* l1b = e_l1_b + (size_t)i * FF;
    const float* l2b = e_l2_b + (size_t)i * E;
    if (i > 0)
      ln_bf16_kernel<<<ROWS / 4, 256, 0, stream>>>(h, e_n1_w + i * E, e_n1_b + i * E, hn_bf);
    mfma_gemm64o_kernel<0, 2><<<dim3(6, 128), 256, 0, stream>>>(
        hn_bf, eqkv_bf + (size_t)i * 3 * E * E, qb, qkb, vtb, 3 * E, E);
    mfma_attn_kernel<<<dim3(SEQ / 64, H, BATCH), 256, 0, stream>>>(qkb, vtb, carr, dr_gamma, attn_bf);
    mfma_gemm32_kernel<0><<<dim3(2, 256), 256, 0, stream>>>(
        attn_bf, eout_bf + (size_t)i * E * E, ob, h, h, nullptr, ROWS, E, E);
    ln_bf16_kernel<<<ROWS / 4, 256, 0, stream>>>(h, e_n2_w + i * E, e_n2_b + i * E, hn_bf);
    mfma_gemm64o_kernel<1, 1><<<dim3(8, 128), 256, 0, stream>>>(
        hn_bf, el1_bf + (size_t)i * FF * E, l1b, mid_bf, nullptr, FF, E);
    if (i < LE - 1)
      mfma_gemm32_kernel<0><<<dim3(2, 256), 256, 0, stream>>>(
          mid_bf, el2_bf + (size_t)i * E * FF, l2b, h, h, nullptr, ROWS, E, FF);
    else
      mfma_gemm32_kernel<1><<<dim3(2, 256), 256, 0, stream>>>(
          mid_bf, el2_bf + (size_t)i * E * FF, l2b, h, h, hn_bf, ROWS, E, FF);
  }
  // h == memory (fp32); hn_bf == bf16(memory)

  rowdot_kernel<<<ROWS, 64, 0, stream>>>(h, parent_w, parent_b, out);

  pool_gather_kernel<<<dim3(BATCH, 8), 256, 0, stream>>>(h, parent_idx, pg);
  cond_kernel<<<BATCH, 256, 0, stream>>>(pg, c1_w, c1_b, c2_w, c2_b, query_embed, tbuf);

  // ALL decoder KV projections in one GEMM (N=1536, bf16 out)
  mfma_gemm64o_kernel<0, 1><<<dim3(12, 128), 256, 0, stream>>>(
      hn_bf, kvw_bf, kvb3, kv_bf, nullptr, 3 * E * 2, E);

  // ---- decoder ----
  for (int i = 0; i < LDN; ++i) {
    dec_ln_gemv_kernel<768, 0><<<dim3(BATCH, 12), 256, 0, stream>>>(
        tbuf, d_n1_w + i * E, d_n1_b + i * E,
        d_sqkv_w + (size_t)i * 3 * E * E, d_sqkv_b + (size_t)i * 3 * E, qkv_t);
    dec_selfattn_sout_kernel<<<dim3(BATCH, 4), 256, 0, stream>>>(
        qkv_t, d_sout_w + (size_t)i * E * E, d_sout_b + (size_t)i * E, tbuf);
    cross_attn_ln_kernel<<<BATCH * H * KQ, 256, 0, stream>>>(
        tbuf, d_n2_w + i * E, d_n2_b + i * E,
        d_cqkv_w + (size_t)i * 3 * E * E, d_cqkv_b + (size_t)i * 3 * E,
        kv_bf, i * 512, i * 512 + 256, attnout_d);
    dec_gemv_resid_kernel<<<dim3(BATCH, 4), 256, 0, stream>>>(
        attnout_d, d_cout_w + (size_t)i * E * E, d_cout_b + (size_t)i * E, tbuf);
    dec_ln_gemv_kernel<1024, 1><<<dim3(BATCH, 16), 256, 0, stream>>>(
        tbuf, d_n3_w + i * E, d_n3_b + i * E,
        d_l1_w + (size_t)i * FF * E, d_l1_b + (size_t)i * FF, dmid);
    dec_ffn2_kernel<<<dim3(BATCH, 4), 256, 0, stream>>>(
        dmid, d_l2_w + (size_t)i * E * FF, d_l2_b + (size_t)i * E, tbuf);
  }

  // heads
  head_kernel<<<TROWS, 256, 0, stream>>>(tbuf, child_w, child_b, o1_w, o1_b, o2_w, o2_b,
                                         out + ROWS, out + ROWS + TROWS * CDIM);
}